// Round 1
// baseline (207.284 us; speedup 1.0000x reference)
//
#include <hip/hip_runtime.h>
#include <hip/hip_bf16.h>
#include <math.h>

// Problem constants (reference: B=32, L=4096, D=256)
constexpr int BB = 32;
constexpr int LL = 4096;
constexpr int DD = 256;

constexpr int BLOCKS_PER_B   = 32;                       // stage-1 blocks per batch
constexpr int WAVES_PER_BLK  = 4;                        // 256 threads
constexpr int PARTS_PER_B    = BLOCKS_PER_B * WAVES_PER_BLK;  // 128 partials per batch
constexpr int ROWS_PER_WAVE  = LL / PARTS_PER_B;         // 32 rows per wave
constexpr int NPART          = BB * PARTS_PER_B;         // 4096 total partials

// Stage 1: fused scores + online softmax + weighted accumulation.
// Each wave processes 32 contiguous rows of one batch, maintaining a running
// (max m, denom s, acc[256] spread as float4 per lane). W·kw + bias is constant
// over l per batch, so it cancels in the softmax and is never computed.
__global__ __launch_bounds__(256) void attn_stage1(
    const float* __restrict__ Q,
    const int*   __restrict__ mask,
    const float* __restrict__ kern,
    float* __restrict__ acc_ws,
    float* __restrict__ m_ws,
    float* __restrict__ s_ws)
{
    const int b    = blockIdx.x / BLOCKS_PER_B;
    const int blk  = blockIdx.x % BLOCKS_PER_B;
    const int wave = threadIdx.x >> 6;
    const int lane = threadIdx.x & 63;
    const int part = blk * WAVES_PER_BLK + wave;        // 0..127 within batch
    const int row0 = part * ROWS_PER_WAVE;

    // kq fragment for this lane: kernel[4*lane .. 4*lane+3]
    const float4 k4 = reinterpret_cast<const float4*>(kern)[lane];

    const float4* __restrict__ q4p =
        reinterpret_cast<const float4*>(Q + (size_t)b * LL * DD)
        + (size_t)row0 * (DD / 4) + lane;
    const int* __restrict__ mrow = mask + b * LL + row0;

    float m = -INFINITY;
    float s = 0.0f;
    float ax = 0.0f, ay = 0.0f, az = 0.0f, aw = 0.0f;

    #pragma unroll 4
    for (int r = 0; r < ROWS_PER_WAVE; ++r) {
        const float4 q = q4p[(size_t)r * (DD / 4)];

        // partial dot, then wave-wide sum (64 lanes cover all 256 d's)
        float d = q.x * k4.x;
        d = fmaf(q.y, k4.y, d);
        d = fmaf(q.z, k4.z, d);
        d = fmaf(q.w, k4.w, d);
        #pragma unroll
        for (int off = 32; off > 0; off >>= 1)
            d += __shfl_xor(d, off, 64);

        const int mk = mrow[r];
        // replicate reference exactly: score - 1e30 (rounds to -1e30 in f32)
        const float score = mk ? d : (d - 1e30f);

        if (score <= m) {
            // fast path: running max unchanged, no rescale (wave-uniform branch)
            const float p = __expf(score - m);
            s += p;
            ax = fmaf(p, q.x, ax);
            ay = fmaf(p, q.y, ay);
            az = fmaf(p, q.z, az);
            aw = fmaf(p, q.w, aw);
        } else {
            // new max: rescale old state. m==-INF first time -> sc==0 (no NaN,
            // since score is always finite >= -1e30).
            const float sc = __expf(m - score);
            m = score;
            s  = fmaf(s,  sc, 1.0f);   // p(new row) == exp(0) == 1
            ax = fmaf(ax, sc, q.x);
            ay = fmaf(ay, sc, q.y);
            az = fmaf(az, sc, q.z);
            aw = fmaf(aw, sc, q.w);
        }
    }

    const size_t p = (size_t)b * PARTS_PER_B + part;
    float4 acc; acc.x = ax; acc.y = ay; acc.z = az; acc.w = aw;
    reinterpret_cast<float4*>(acc_ws)[p * (DD / 4) + lane] = acc;
    if (lane == 0) {
        m_ws[p] = m;
        s_ws[p] = s;
    }
}

// Stage 2: merge the 128 partials of each batch, normalize, write out[b, :].
__global__ __launch_bounds__(256) void attn_stage2(
    const float* __restrict__ acc_ws,
    const float* __restrict__ m_ws,
    const float* __restrict__ s_ws,
    float* __restrict__ out)
{
    const int b = blockIdx.x;
    const int t = threadIdx.x;   // t == output dim d

    __shared__ float ml[PARTS_PER_B];
    __shared__ float sl[PARTS_PER_B];
    __shared__ float el[PARTS_PER_B];

    if (t < PARTS_PER_B) {
        ml[t] = m_ws[(size_t)b * PARTS_PER_B + t];
        sl[t] = s_ws[(size_t)b * PARTS_PER_B + t];
    }
    __syncthreads();

    float M = -INFINITY;
    #pragma unroll 8
    for (int p = 0; p < PARTS_PER_B; ++p)
        M = fmaxf(M, ml[p]);   // broadcast LDS reads, every thread same value

    if (t < PARTS_PER_B)
        el[t] = __expf(ml[t] - M);
    __syncthreads();

    float S = 0.0f;
    #pragma unroll 8
    for (int p = 0; p < PARTS_PER_B; ++p)
        S = fmaf(el[p], sl[p], S);
    const float inv = 1.0f / S;

    float sum = 0.0f;
    const float* __restrict__ ap = acc_ws + (size_t)b * PARTS_PER_B * DD + t;
    #pragma unroll 8
    for (int p = 0; p < PARTS_PER_B; ++p)
        sum = fmaf(el[p], ap[(size_t)p * DD], sum);   // coalesced across threads

    out[b * DD + t] = sum * inv;
}

extern "C" void kernel_launch(void* const* d_in, const int* in_sizes, int n_in,
                              void* d_out, int out_size, void* d_ws, size_t ws_size,
                              hipStream_t stream)
{
    // setup_inputs order: Q (f32), W (f32, unused), mask (int), kernel (f32), bias (f32, unused)
    const float* Q    = (const float*)d_in[0];
    const int*   mask = (const int*)  d_in[2];
    const float* kern = (const float*)d_in[3];   // first DD floats are kq
    float*       out  = (float*)d_out;

    // workspace layout: acc[NPART][DD] | m[NPART] | s[NPART]  (~4.03 MB)
    float* acc_ws = (float*)d_ws;
    float* m_ws   = acc_ws + (size_t)NPART * DD;
    float* s_ws   = m_ws + NPART;

    hipLaunchKernelGGL(attn_stage1, dim3(BB * BLOCKS_PER_B), dim3(256), 0, stream,
                       Q, mask, kern, acc_ws, m_ws, s_ws);
    hipLaunchKernelGGL(attn_stage2, dim3(BB), dim3(256), 0, stream,
                       acc_ws, m_ws, s_ws, out);
}